// Round 3
// baseline (545.804 us; speedup 1.0000x reference)
//
#include <hip/hip_runtime.h>
#include <hip/hip_bf16.h>

// B=8, R=8, N=1024, D_IN=D_OUT=256, all fp32 in/out.
// prep_w : Wt[r][e][d] = bf16(W[r][d][e])        (scratch: first 1 MB of d_out, pre-memset)
// stage 1: sup[b,r,e,n] = bf16(x@W + bias)        (ws, 32 MB) — barrier-free direct-frag MFMA
// stage 2: out[b,m,e] += adj[b,r,m,n]*sup[b,r,e,n] — barrier-free direct-frag MFMA, split-K=8
// stage 3: ReLU in place.
//
// Rationale (R3): stage 2 moves 278 MB for 34 GFLOP -> memory-bound 30:1. LDS+__syncthreads
// forces vmcnt(0) drains per K-step (m97 plateau mechanism). So: no LDS, no barriers —
// fragments load straight from global (A: 16 rows x 128B contiguous per wave, coalesced),
// latency hidden by cross-wave TLP + register ping-pong prefetch.

#define Rr 8
#define Nn 1024
#define Dd 256

typedef __attribute__((ext_vector_type(8))) short short8;
typedef __attribute__((ext_vector_type(4))) float f32x4;

__device__ __forceinline__ short f2bf(float f) {
    unsigned u = __builtin_bit_cast(unsigned, f);
    u += 0x7fffu + ((u >> 16) & 1u);   // RNE
    return (short)(u >> 16);
}

// ---------------- prep: Wt[r][e][d] bf16 <- W[r][d][e] f32 ----------------
__global__ void prep_w_kernel(const float* __restrict__ W, short* __restrict__ Wt) {
    __shared__ short T[64][72];
    const int tid = threadIdx.x;
    const int et = blockIdx.x, dt = blockIdx.y, r = blockIdx.z;
    const float* Wr = W + ((size_t)r * Dd + dt * 64) * Dd + et * 64;
    #pragma unroll
    for (int i = 0; i < 4; ++i) {
        int idx = tid + i * 256;
        int d_l = idx >> 4;
        int e4  = (idx & 15) * 4;
        f32x4 v = *(const f32x4*)(Wr + d_l * Dd + e4);
        T[e4 + 0][d_l] = f2bf(v[0]);
        T[e4 + 1][d_l] = f2bf(v[1]);
        T[e4 + 2][d_l] = f2bf(v[2]);
        T[e4 + 3][d_l] = f2bf(v[3]);
    }
    __syncthreads();
    short* o = Wt + ((size_t)r * Dd + et * 64) * Dd + dt * 64;
    #pragma unroll
    for (int i = 0; i < 2; ++i) {
        int idx = tid + i * 256;
        *(short8*)(o + (idx >> 3) * Dd + (idx & 7) * 8) = *(const short8*)&T[idx >> 3][(idx & 7) * 8];
    }
}

// ---------------- Stage 1: sup[b,r,e,n] = bf16(Wt @ x^T + bias) ----------------
// grid (r=8, n_t=16, b=8) = 1024 blocks; block = 4 waves, wave -> e-range wave*64, n-range n_t*64.
__global__ __launch_bounds__(256) void support_kernel(
        const float* __restrict__ x, const short* __restrict__ Wt,
        const float* __restrict__ bias, short* __restrict__ sup) {
    const int tid = threadIdx.x;
    const int wave = tid >> 6, lane = tid & 63;
    const int quad = lane >> 4, l16 = lane & 15;
    const int r = blockIdx.x, n_t = blockIdx.y, b = blockIdx.z;
    const int e0 = wave * 64, n0 = n_t * 64;

    const short* wp = Wt + (size_t)r * Dd * Dd + (size_t)e0 * Dd;
    const float* xb = x + ((size_t)b * Nn + n0) * Dd;

    short8 av[4];
    f32x4 xlo[4], xhi[4];
    auto load = [&](int d0) {
        #pragma unroll
        for (int i = 0; i < 4; ++i)
            av[i] = *(const short8*)(wp + (i * 16 + l16) * Dd + d0 + quad * 8);
        #pragma unroll
        for (int j = 0; j < 4; ++j) {
            const float* p = xb + (size_t)(j * 16 + l16) * Dd + d0 + quad * 8;
            xlo[j] = *(const f32x4*)p;
            xhi[j] = *(const f32x4*)(p + 4);
        }
    };

    f32x4 acc[4][4] = {};
    load(0);
    for (int it = 0; it < 8; ++it) {
        short8 a[4], bfr[4];
        #pragma unroll
        for (int i = 0; i < 4; ++i) a[i] = av[i];
        #pragma unroll
        for (int j = 0; j < 4; ++j) {
            short8 t;
            t[0] = f2bf(xlo[j][0]); t[1] = f2bf(xlo[j][1]);
            t[2] = f2bf(xlo[j][2]); t[3] = f2bf(xlo[j][3]);
            t[4] = f2bf(xhi[j][0]); t[5] = f2bf(xhi[j][1]);
            t[6] = f2bf(xhi[j][2]); t[7] = f2bf(xhi[j][3]);
            bfr[j] = t;
        }
        if (it < 7) load((it + 1) * 32);
        #pragma unroll
        for (int i = 0; i < 4; ++i)
            #pragma unroll
            for (int j = 0; j < 4; ++j)
                acc[i][j] = __builtin_amdgcn_mfma_f32_16x16x32_bf16(a[i], bfr[j], acc[i][j], 0, 0, 0);
    }

    // C[row=e][col=n]; add bias; bf16 store.
    short* sb = sup + (((size_t)(b * Rr + r) * Dd) << 10);
    #pragma unroll
    for (int i = 0; i < 4; ++i)
        #pragma unroll
        for (int reg = 0; reg < 4; ++reg) {
            int e = e0 + i * 16 + quad * 4 + reg;
            float bv = bias[r * Dd + e];
            #pragma unroll
            for (int j = 0; j < 4; ++j) {
                int n = n0 + j * 16 + l16;
                sb[((size_t)e << 10) + n] = f2bf(acc[i][j][reg] + bv);
            }
        }
}

// ---------------- Stage 2: out += adj @ sup^T, barrier-free, split-K=8 ----------------
// grid (r=8, m_t=16, b=8) = 1024 blocks; block = 4 waves, wave -> e-range wave*64, m-range m_t*64.
// A-frag: adj rows, 2x dwordx4 fp32 per frag (wave: 16 rows x 128B contiguous -> coalesced).
// B-frag: sup rows (bf16), 1x dwordx4 per frag.
__global__ __launch_bounds__(256) void gcn_gemm_kernel(
        const float* __restrict__ adj, const short* __restrict__ sup,
        float* __restrict__ out) {
    const int tid = threadIdx.x;
    const int wave = tid >> 6, lane = tid & 63;
    const int quad = lane >> 4, l16 = lane & 15;
    const int r = blockIdx.x, m_t = blockIdx.y, b = blockIdx.z;
    const int e0 = wave * 64;

    const float* ap = adj + ((size_t)((b * Rr + r) * Nn + m_t * 64)) * Nn;
    const short* bp = sup + (((size_t)((b * Rr + r) * Dd + e0)) << 10);

    f32x4 alo[4], ahi[4];
    short8 bs[4];
    auto load = [&](int kk) {
        #pragma unroll
        for (int i = 0; i < 4; ++i) {
            const float* p = ap + (size_t)(i * 16 + l16) * Nn + kk + quad * 8;
            alo[i] = *(const f32x4*)p;
            ahi[i] = *(const f32x4*)(p + 4);
        }
        #pragma unroll
        for (int j = 0; j < 4; ++j)
            bs[j] = *(const short8*)(bp + ((size_t)(j * 16 + l16) << 10) + kk + quad * 8);
    };

    f32x4 acc[4][4] = {};
    load(0);
    for (int it = 0; it < 32; ++it) {
        short8 a[4], bfr[4];
        #pragma unroll
        for (int i = 0; i < 4; ++i) {
            short8 t;
            t[0] = f2bf(alo[i][0]); t[1] = f2bf(alo[i][1]);
            t[2] = f2bf(alo[i][2]); t[3] = f2bf(alo[i][3]);
            t[4] = f2bf(ahi[i][0]); t[5] = f2bf(ahi[i][1]);
            t[6] = f2bf(ahi[i][2]); t[7] = f2bf(ahi[i][3]);
            a[i] = t;
            bfr[i] = bs[i];
        }
        if (it < 31) load((it + 1) * 32);   // no barrier anywhere: these fly during the MFMAs
        #pragma unroll
        for (int i = 0; i < 4; ++i)
            #pragma unroll
            for (int j = 0; j < 4; ++j)
                acc[i][j] = __builtin_amdgcn_mfma_f32_16x16x32_bf16(a[i], bfr[j], acc[i][j], 0, 0, 0);
    }

    // C[row=m][col=e]; split-K partial -> atomicAdd into zeroed out.
    float* ob = out + ((size_t)b * Nn + m_t * 64) * Dd + e0;
    #pragma unroll
    for (int i = 0; i < 4; ++i)
        #pragma unroll
        for (int reg = 0; reg < 4; ++reg) {
            int m_l = i * 16 + quad * 4 + reg;
            #pragma unroll
            for (int j = 0; j < 4; ++j)
                atomicAdd(ob + (size_t)m_l * Dd + j * 16 + l16, acc[i][j][reg]);
        }
}

// ---------------- Stage 3: ReLU in place ----------------
__global__ void relu_kernel(float* __restrict__ out, int n4) {
    int i = blockIdx.x * blockDim.x + threadIdx.x;
    if (i < n4) {
        f32x4* p = (f32x4*)out;
        f32x4 v = p[i];
        v[0] = fmaxf(v[0], 0.f); v[1] = fmaxf(v[1], 0.f);
        v[2] = fmaxf(v[2], 0.f); v[3] = fmaxf(v[3], 0.f);
        p[i] = v;
    }
}

extern "C" void kernel_launch(void* const* d_in, const int* in_sizes, int n_in,
                              void* d_out, int out_size, void* d_ws, size_t ws_size,
                              hipStream_t stream) {
    const float* x    = (const float*)d_in[0];
    const float* adj  = (const float*)d_in[1];
    const float* W    = (const float*)d_in[2];
    const float* bias = (const float*)d_in[3];
    float* out = (float*)d_out;
    short* sup = (short*)d_ws;            // 32 MB of ws
    short* Wt  = (short*)d_out;           // 1 MB scratch inside d_out, consumed before memset

    prep_w_kernel<<<dim3(4, 4, 8), 256, 0, stream>>>(W, Wt);
    support_kernel<<<dim3(8, 16, 8), 256, 0, stream>>>(x, Wt, bias, sup);
    hipMemsetAsync(d_out, 0, (size_t)out_size * sizeof(float), stream);
    gcn_gemm_kernel<<<dim3(8, 16, 8), 256, 0, stream>>>(adj, sup, out);
    relu_kernel<<<(out_size / 4 + 255) / 256, 256, 0, stream>>>(out, out_size / 4);
}

// Round 4
// 458.899 us; speedup vs baseline: 1.1894x; 1.1894x over previous
//
#include <hip/hip_runtime.h>
#include <hip/hip_bf16.h>

// B=8, R=8, N=1024, D_IN=D_OUT=256, all fp32 in/out.
// prep_w : Wt[r][e][d] = bf16(W[r][d][e])        (scratch: first 1 MB of d_out, pre-memset)
// stage 1: sup[b,r,e,n] = bf16(x@W + bias)        (ws, 32 MB) — global_load_lds staging
// stage 2: out[b,m,e] += adj[b,r,m,n]*sup[b,r,e,n] — global_load_lds staging, split-K=8
// stage 3: ReLU in place.
//
// R4 rationale: R3's direct-frag loads thrashed L1 (16 rows x 4KB/2KB stride = same set)
// and held only 1 iter of prefetch. m97-style global_load_lds stages the full 24KB tile
// in 6 instrs/wave with no VGPR round-trip and no staging VALU (measured ~8 B/cyc/CU
// through the same 2-barrier loop). adj stays fp32 in LDS; convert on the frag path.

#define Rr 8
#define Nn 1024
#define Dd 256

typedef __attribute__((ext_vector_type(8))) short short8;
typedef __attribute__((ext_vector_type(4))) float f32x4;

__device__ __forceinline__ short f2bf(float f) {
    unsigned u = __builtin_bit_cast(unsigned, f);
    u += 0x7fffu + ((u >> 16) & 1u);   // RNE
    return (short)(u >> 16);
}

__device__ __forceinline__ void gload_lds16(const void* g, void* l) {
    __builtin_amdgcn_global_load_lds(
        (const __attribute__((address_space(1))) unsigned int*)g,
        (__attribute__((address_space(3))) unsigned int*)l, 16, 0, 0);
}

// ---------------- prep: Wt[r][e][d] bf16 <- W[r][d][e] f32 ----------------
__global__ void prep_w_kernel(const float* __restrict__ W, short* __restrict__ Wt) {
    __shared__ short T[64][72];
    const int tid = threadIdx.x;
    const int et = blockIdx.x, dt = blockIdx.y, r = blockIdx.z;
    const float* Wr = W + ((size_t)r * Dd + dt * 64) * Dd + et * 64;
    #pragma unroll
    for (int i = 0; i < 4; ++i) {
        int idx = tid + i * 256;
        int d_l = idx >> 4;
        int e4  = (idx & 15) * 4;
        f32x4 v = *(const f32x4*)(Wr + d_l * Dd + e4);
        T[e4 + 0][d_l] = f2bf(v[0]);
        T[e4 + 1][d_l] = f2bf(v[1]);
        T[e4 + 2][d_l] = f2bf(v[2]);
        T[e4 + 3][d_l] = f2bf(v[3]);
    }
    __syncthreads();
    short* o = Wt + ((size_t)r * Dd + et * 64) * Dd + dt * 64;
    #pragma unroll
    for (int i = 0; i < 2; ++i) {
        int idx = tid + i * 256;
        *(short8*)(o + (idx >> 3) * Dd + (idx & 7) * 8) = *(const short8*)&T[idx >> 3][(idx & 7) * 8];
    }
}

// ---------------- Stage 1: sup[b,r,e,n] = bf16(Wt @ x^T + bias) ----------------
// grid (2 e_t, 8 n_t, 64 br), block 256 = 4 waves (2e x 2n), tile 128e x 128n, K=256, BK=32.
// A = Wt bf16 (DMA direct), B = x fp32 (DMA + frag-path cvt).
__global__ __launch_bounds__(256, 3) void support_kernel(
        const float* __restrict__ x, const short* __restrict__ Wt,
        const float* __restrict__ bias, short* __restrict__ sup) {
    __shared__ short As[128 * 32];   // [e][d] bf16, 8 KB
    __shared__ float Bs[128 * 32];   // [n][d] fp32, 16 KB

    const int tid = threadIdx.x;
    const int wave = tid >> 6, lane = tid & 63;
    const int quad = lane >> 4, l16 = lane & 15;
    const int e_t = blockIdx.x, n_t = blockIdx.y, br = blockIdx.z;
    const int b = br >> 3, r = br & 7;
    const int we = wave & 1, wn = wave >> 1;

    const short* wp = Wt + ((size_t)r * Dd + e_t * 128) * Dd;
    const float* xb = x + ((size_t)b * Nn + n_t * 128) * Dd;

    f32x4 acc[4][4] = {};

    for (int it = 0; it < 8; ++it) {
        const int d0 = it * 32;
        // A: 2 DMA/wave, 16 bf16-rows per instr (row = 64B).
        #pragma unroll
        for (int i = 0; i < 2; ++i) {
            int row = 16 * wave + 64 * i;
            gload_lds16(wp + (size_t)(row + (lane >> 2)) * Dd + d0 + (lane & 3) * 8,
                        &As[row * 32]);
        }
        // B: 4 DMA/wave, 8 fp32-rows per instr (row = 128B).
        #pragma unroll
        for (int i = 0; i < 4; ++i) {
            int row = 8 * wave + 32 * i;
            gload_lds16(xb + (size_t)(row + (lane >> 3)) * Dd + d0 + (lane & 7) * 4,
                        &Bs[row * 32]);
        }
        __syncthreads();
        short8 a[4], bfr[4];
        #pragma unroll
        for (int i = 0; i < 4; ++i)
            a[i] = *(const short8*)&As[(we * 64 + i * 16 + l16) * 32 + quad * 8];
        #pragma unroll
        for (int j = 0; j < 4; ++j) {
            const float* p = &Bs[(wn * 64 + j * 16 + l16) * 32 + quad * 8];
            f32x4 lo = *(const f32x4*)p, hi = *(const f32x4*)(p + 4);
            short8 t;
            t[0] = f2bf(lo[0]); t[1] = f2bf(lo[1]); t[2] = f2bf(lo[2]); t[3] = f2bf(lo[3]);
            t[4] = f2bf(hi[0]); t[5] = f2bf(hi[1]); t[6] = f2bf(hi[2]); t[7] = f2bf(hi[3]);
            bfr[j] = t;
        }
        #pragma unroll
        for (int i = 0; i < 4; ++i)
            #pragma unroll
            for (int j = 0; j < 4; ++j)
                acc[i][j] = __builtin_amdgcn_mfma_f32_16x16x32_bf16(a[i], bfr[j], acc[i][j], 0, 0, 0);
        __syncthreads();
    }

    // Epilogue: C[row=e][col=n]; add bias; bf16 store to sup[(b,r),e,n].
    #pragma unroll
    for (int i = 0; i < 4; ++i)
        #pragma unroll
        for (int reg = 0; reg < 4; ++reg) {
            int e = e_t * 128 + we * 64 + i * 16 + quad * 4 + reg;
            float bv = bias[r * Dd + e];
            #pragma unroll
            for (int j = 0; j < 4; ++j) {
                int n = n_t * 128 + wn * 64 + j * 16 + l16;
                sup[(((b * Rr + r) * Dd + e) << 10) + n] = f2bf(acc[i][j][reg] + bv);
            }
        }
}

// ---------------- Stage 2: out += adj @ sup^T (split-K=8) ----------------
// grid (16, 8, 8) = 1024 blocks; block 256 = 4 waves (2m x 2e), tile 128m x 128e, BK=32.
// A = adj fp32 (DMA + frag-path cvt), B = sup bf16 (DMA direct).
__global__ __launch_bounds__(256, 3) void gcn_gemm_kernel(
        const float* __restrict__ adj, const short* __restrict__ sup,
        float* __restrict__ out) {
    __shared__ float Aa[128 * 32];   // [m][k] fp32, 16 KB
    __shared__ short Bs[128 * 32];   // [e][k] bf16, 8 KB

    const int tid = threadIdx.x;
    const int wave = tid >> 6, lane = tid & 63;
    const int quad = lane >> 4, l16 = lane & 15;
    const int e2 = blockIdx.x & 1, r = blockIdx.x >> 1;
    const int m_t = blockIdx.y, b = blockIdx.z;
    const int wm = wave >> 1, we = wave & 1;

    const float* ap = adj + ((size_t)((b * Rr + r) * Nn + m_t * 128)) * Nn;
    const short* bp = sup + (((size_t)((b * Rr + r) * Dd + e2 * 128)) << 10);

    f32x4 acc[4][4] = {};

    for (int it = 0; it < 32; ++it) {
        const int kk = it * 32;
        // A: 4 DMA/wave, 8 fp32-rows per instr.
        #pragma unroll
        for (int i = 0; i < 4; ++i) {
            int row = 8 * wave + 32 * i;
            gload_lds16(ap + (size_t)(row + (lane >> 3)) * Nn + kk + (lane & 7) * 4,
                        &Aa[row * 32]);
        }
        // B: 2 DMA/wave, 16 bf16-rows per instr.
        #pragma unroll
        for (int i = 0; i < 2; ++i) {
            int row = 16 * wave + 64 * i;
            gload_lds16(bp + (((size_t)(row + (lane >> 2))) << 10) + kk + (lane & 3) * 8,
                        &Bs[row * 32]);
        }
        __syncthreads();
        short8 a[4], bfr[4];
        #pragma unroll
        for (int i = 0; i < 4; ++i) {
            const float* p = &Aa[(wm * 64 + i * 16 + l16) * 32 + quad * 8];
            f32x4 lo = *(const f32x4*)p, hi = *(const f32x4*)(p + 4);
            short8 t;
            t[0] = f2bf(lo[0]); t[1] = f2bf(lo[1]); t[2] = f2bf(lo[2]); t[3] = f2bf(lo[3]);
            t[4] = f2bf(hi[0]); t[5] = f2bf(hi[1]); t[6] = f2bf(hi[2]); t[7] = f2bf(hi[3]);
            a[i] = t;
        }
        #pragma unroll
        for (int j = 0; j < 4; ++j)
            bfr[j] = *(const short8*)&Bs[(we * 64 + j * 16 + l16) * 32 + quad * 8];
        #pragma unroll
        for (int i = 0; i < 4; ++i)
            #pragma unroll
            for (int j = 0; j < 4; ++j)
                acc[i][j] = __builtin_amdgcn_mfma_f32_16x16x32_bf16(a[i], bfr[j], acc[i][j], 0, 0, 0);
        __syncthreads();
    }

    // Epilogue: C[row=m][col=e]; split-K partial -> atomicAdd into zeroed out.
    float* ob = out + ((size_t)b * Nn + m_t * 128) * Dd + e2 * 128;
    #pragma unroll
    for (int i = 0; i < 4; ++i)
        #pragma unroll
        for (int reg = 0; reg < 4; ++reg) {
            int m_l = wm * 64 + i * 16 + quad * 4 + reg;
            #pragma unroll
            for (int j = 0; j < 4; ++j)
                atomicAdd(ob + (size_t)m_l * Dd + we * 64 + j * 16 + l16, acc[i][j][reg]);
        }
}

// ---------------- Stage 3: ReLU in place ----------------
__global__ void relu_kernel(float* __restrict__ out, int n4) {
    int i = blockIdx.x * blockDim.x + threadIdx.x;
    if (i < n4) {
        f32x4* p = (f32x4*)out;
        f32x4 v = p[i];
        v[0] = fmaxf(v[0], 0.f); v[1] = fmaxf(v[1], 0.f);
        v[2] = fmaxf(v[2], 0.f); v[3] = fmaxf(v[3], 0.f);
        p[i] = v;
    }
}

extern "C" void kernel_launch(void* const* d_in, const int* in_sizes, int n_in,
                              void* d_out, int out_size, void* d_ws, size_t ws_size,
                              hipStream_t stream) {
    const float* x    = (const float*)d_in[0];
    const float* adj  = (const float*)d_in[1];
    const float* W    = (const float*)d_in[2];
    const float* bias = (const float*)d_in[3];
    float* out = (float*)d_out;
    short* sup = (short*)d_ws;            // 32 MB of ws
    short* Wt  = (short*)d_out;           // 1 MB scratch inside d_out, consumed before memset

    prep_w_kernel<<<dim3(4, 4, 8), 256, 0, stream>>>(W, Wt);
    support_kernel<<<dim3(2, 8, 64), 256, 0, stream>>>(x, Wt, bias, sup);
    hipMemsetAsync(d_out, 0, (size_t)out_size * sizeof(float), stream);
    gcn_gemm_kernel<<<dim3(16, 8, 8), 256, 0, stream>>>(adj, sup, out);
    relu_kernel<<<(out_size / 4 + 255) / 256, 256, 0, stream>>>(out, out_size / 4);
}

// Round 5
// 449.630 us; speedup vs baseline: 1.2139x; 1.0206x over previous
//
#include <hip/hip_runtime.h>
#include <hip/hip_bf16.h>

// B=8, R=8, N=1024, D_IN=D_OUT=256, all fp32 in/out.
// prep_w : Wt[r][e][d] = bf16(W[r][d][e])         (scratch: first 1 MB of d_out, pre-memset)
// stage 1: sup[b,r,e,n] = bf16(x@W + bias)         (ws, 32 MB)
// stage 2: out[b,m,e] += adj[b,r,m,n]*sup[b,r,e,n]  (bf16 MFMA, split-K=8, atomicAdd)
// stage 3: ReLU in place.
//
// R5: VGPR-staged bf16 tiles at pitch 40 (2-way banks = free; DMA staging forced 8/16-way
// conflicts). Double-buffered LDS with ONE barrier/iter; global loads issued AFTER the
// barrier so they overlap frag-reads+MFMA+next-stage instead of being drained by vmcnt(0).
// gemm grid: e2-pair blocks differ by 8 in linear index -> same XCD -> adj tile L2-shared.

#define Rr 8
#define Nn 1024
#define Dd 256
#define PITCH 40

typedef __attribute__((ext_vector_type(8))) short short8;
typedef __attribute__((ext_vector_type(4))) float f32x4;

__device__ __forceinline__ short f2bf(float f) {
    unsigned u = __builtin_bit_cast(unsigned, f);
    u += 0x7fffu + ((u >> 16) & 1u);   // RNE
    return (short)(u >> 16);
}

// ---------------- prep: Wt[r][e][d] bf16 <- W[r][d][e] f32 ----------------
__global__ void prep_w_kernel(const float* __restrict__ W, short* __restrict__ Wt) {
    __shared__ short T[64][72];
    const int tid = threadIdx.x;
    const int et = blockIdx.x, dt = blockIdx.y, r = blockIdx.z;
    const float* Wr = W + ((size_t)r * Dd + dt * 64) * Dd + et * 64;
    #pragma unroll
    for (int i = 0; i < 4; ++i) {
        int idx = tid + i * 256;
        int d_l = idx >> 4;
        int e4  = (idx & 15) * 4;
        f32x4 v = *(const f32x4*)(Wr + d_l * Dd + e4);
        T[e4 + 0][d_l] = f2bf(v[0]);
        T[e4 + 1][d_l] = f2bf(v[1]);
        T[e4 + 2][d_l] = f2bf(v[2]);
        T[e4 + 3][d_l] = f2bf(v[3]);
    }
    __syncthreads();
    short* o = Wt + ((size_t)r * Dd + et * 64) * Dd + dt * 64;
    #pragma unroll
    for (int i = 0; i < 2; ++i) {
        int idx = tid + i * 256;
        *(short8*)(o + (idx >> 3) * Dd + (idx & 7) * 8) = *(const short8*)&T[idx >> 3][(idx & 7) * 8];
    }
}

// ---------------- Stage 1: sup[b,r,e,n] = bf16(Wt @ x^T + bias) ----------------
// grid (2 e_t, 8 n_t, 64 br), block 256 = 4 waves (2e x 2n), tile 128e x 128n, BK=32, 8 iters.
__global__ __launch_bounds__(256, 4) void support_kernel(
        const float* __restrict__ x, const short* __restrict__ Wt,
        const float* __restrict__ bias, short* __restrict__ sup) {
    __shared__ short As[2][128 * PITCH];   // [e][d] bf16
    __shared__ short Bs[2][128 * PITCH];   // [n][d] bf16

    const int tid = threadIdx.x;
    const int wave = tid >> 6, lane = tid & 63;
    const int quad = lane >> 4, l16 = lane & 15;
    const int e_t = blockIdx.x, n_t = blockIdx.y, br = blockIdx.z;
    const int b = br >> 3, r = br & 7;
    const int we = wave & 1, wn = wave >> 1;

    const short* wp = Wt + ((size_t)r * Dd + e_t * 128) * Dd;
    const float* xb = x + ((size_t)b * Nn + n_t * 128) * Dd;

    short8 aw[2];
    f32x4 xv[4];
    auto gload = [&](int d0) {
        #pragma unroll
        for (int i = 0; i < 2; ++i) {
            int idx = tid + i * 256;
            aw[i] = *(const short8*)(wp + (idx >> 2) * Dd + d0 + (idx & 3) * 8);
        }
        #pragma unroll
        for (int i = 0; i < 2; ++i) {
            int idx = tid + i * 256;
            const float* p = xb + (idx >> 2) * Dd + d0 + (idx & 3) * 8;
            xv[2 * i]     = *(const f32x4*)p;
            xv[2 * i + 1] = *(const f32x4*)(p + 4);
        }
    };
    auto stage = [&](int buf) {
        #pragma unroll
        for (int i = 0; i < 2; ++i) {
            int idx = tid + i * 256;
            *(short8*)&As[buf][(idx >> 2) * PITCH + (idx & 3) * 8] = aw[i];
        }
        #pragma unroll
        for (int i = 0; i < 2; ++i) {
            int idx = tid + i * 256;
            short8 t;
            t[0] = f2bf(xv[2 * i][0]); t[1] = f2bf(xv[2 * i][1]);
            t[2] = f2bf(xv[2 * i][2]); t[3] = f2bf(xv[2 * i][3]);
            t[4] = f2bf(xv[2 * i + 1][0]); t[5] = f2bf(xv[2 * i + 1][1]);
            t[6] = f2bf(xv[2 * i + 1][2]); t[7] = f2bf(xv[2 * i + 1][3]);
            *(short8*)&Bs[buf][(idx >> 2) * PITCH + (idx & 3) * 8] = t;
        }
    };

    f32x4 acc[4][4] = {};
    gload(0);
    for (int it = 0; it < 8; ++it) {
        const int buf = it & 1;
        stage(buf);
        __syncthreads();
        if (it < 7) gload((it + 1) * 32);   // flies through frag reads + MFMA + next stage
        short8 a[4], bfr[4];
        #pragma unroll
        for (int i = 0; i < 4; ++i)
            a[i] = *(const short8*)&As[buf][(we * 64 + i * 16 + l16) * PITCH + quad * 8];
        #pragma unroll
        for (int j = 0; j < 4; ++j)
            bfr[j] = *(const short8*)&Bs[buf][(wn * 64 + j * 16 + l16) * PITCH + quad * 8];
        #pragma unroll
        for (int i = 0; i < 4; ++i)
            #pragma unroll
            for (int j = 0; j < 4; ++j)
                acc[i][j] = __builtin_amdgcn_mfma_f32_16x16x32_bf16(a[i], bfr[j], acc[i][j], 0, 0, 0);
    }

    // Epilogue: C[row=e][col=n]; add bias; bf16 store to sup[(b,r),e,n].
    #pragma unroll
    for (int i = 0; i < 4; ++i)
        #pragma unroll
        for (int reg = 0; reg < 4; ++reg) {
            int e = e_t * 128 + we * 64 + i * 16 + quad * 4 + reg;
            float bv = bias[r * Dd + e];
            #pragma unroll
            for (int j = 0; j < 4; ++j) {
                int n = n_t * 128 + wn * 64 + j * 16 + l16;
                sup[(((b * Rr + r) * Dd + e) << 10) + n] = f2bf(acc[i][j][reg] + bv);
            }
        }
}

// ---------------- Stage 2: out += adj @ sup^T (split-K=8) ----------------
// grid (16, 8, 8); bx: r = bx&7, e2 = bx>>3 -> e2-pairs differ by 8 -> same XCD (L2-share adj).
// block 256 = 4 waves (2m x 2e), tile 128m x 128e, BK=32, 32 iters.
__global__ __launch_bounds__(256, 4) void gcn_gemm_kernel(
        const float* __restrict__ adj, const short* __restrict__ sup,
        float* __restrict__ out) {
    __shared__ short Aa[2][128 * PITCH];   // [m][k] bf16 (cvt from fp32 adj)
    __shared__ short Bs[2][128 * PITCH];   // [e][k] bf16 (sup passthrough)

    const int tid = threadIdx.x;
    const int wave = tid >> 6, lane = tid & 63;
    const int quad = lane >> 4, l16 = lane & 15;
    const int r = blockIdx.x & 7, e2 = blockIdx.x >> 3;
    const int m_t = blockIdx.y, b = blockIdx.z;
    const int wm = wave >> 1, we = wave & 1;

    const float* ap = adj + ((size_t)((b * Rr + r) * Nn + m_t * 128)) * Nn;
    const short* bp = sup + (((size_t)((b * Rr + r) * Dd + e2 * 128)) << 10);

    f32x4 av[4];
    short8 bv[2];
    auto gload = [&](int kk) {
        #pragma unroll
        for (int i = 0; i < 2; ++i) {
            int idx = tid + i * 256;
            const float* p = ap + (size_t)(idx >> 2) * Nn + kk + (idx & 3) * 8;
            av[2 * i]     = *(const f32x4*)p;
            av[2 * i + 1] = *(const f32x4*)(p + 4);
        }
        #pragma unroll
        for (int i = 0; i < 2; ++i) {
            int idx = tid + i * 256;
            bv[i] = *(const short8*)(bp + ((size_t)(idx >> 2) << 10) + kk + (idx & 3) * 8);
        }
    };
    auto stage = [&](int buf) {
        #pragma unroll
        for (int i = 0; i < 2; ++i) {
            int idx = tid + i * 256;
            short8 t;
            t[0] = f2bf(av[2 * i][0]); t[1] = f2bf(av[2 * i][1]);
            t[2] = f2bf(av[2 * i][2]); t[3] = f2bf(av[2 * i][3]);
            t[4] = f2bf(av[2 * i + 1][0]); t[5] = f2bf(av[2 * i + 1][1]);
            t[6] = f2bf(av[2 * i + 1][2]); t[7] = f2bf(av[2 * i + 1][3]);
            *(short8*)&Aa[buf][(idx >> 2) * PITCH + (idx & 3) * 8] = t;
        }
        #pragma unroll
        for (int i = 0; i < 2; ++i) {
            int idx = tid + i * 256;
            *(short8*)&Bs[buf][(idx >> 2) * PITCH + (idx & 3) * 8] = bv[i];
        }
    };

    f32x4 acc[4][4] = {};
    gload(0);
    for (int it = 0; it < 32; ++it) {
        const int buf = it & 1;
        stage(buf);
        __syncthreads();
        if (it < 31) gload((it + 1) * 32);  // flies through frag reads + MFMA + next stage
        short8 a[4], bfr[4];
        #pragma unroll
        for (int i = 0; i < 4; ++i)
            a[i] = *(const short8*)&Aa[buf][(wm * 64 + i * 16 + l16) * PITCH + quad * 8];
        #pragma unroll
        for (int j = 0; j < 4; ++j)
            bfr[j] = *(const short8*)&Bs[buf][(we * 64 + j * 16 + l16) * PITCH + quad * 8];
        #pragma unroll
        for (int i = 0; i < 4; ++i)
            #pragma unroll
            for (int j = 0; j < 4; ++j)
                acc[i][j] = __builtin_amdgcn_mfma_f32_16x16x32_bf16(a[i], bfr[j], acc[i][j], 0, 0, 0);
    }

    // Epilogue: C[row=m][col=e]; split-K partial -> atomicAdd into zeroed out.
    float* ob = out + ((size_t)b * Nn + m_t * 128) * Dd + e2 * 128;
    #pragma unroll
    for (int i = 0; i < 4; ++i)
        #pragma unroll
        for (int reg = 0; reg < 4; ++reg) {
            int m_l = wm * 64 + i * 16 + quad * 4 + reg;
            #pragma unroll
            for (int j = 0; j < 4; ++j)
                atomicAdd(ob + (size_t)m_l * Dd + we * 64 + j * 16 + l16, acc[i][j][reg]);
        }
}

// ---------------- Stage 3: ReLU in place ----------------
__global__ void relu_kernel(float* __restrict__ out, int n4) {
    int i = blockIdx.x * blockDim.x + threadIdx.x;
    if (i < n4) {
        f32x4* p = (f32x4*)out;
        f32x4 v = p[i];
        v[0] = fmaxf(v[0], 0.f); v[1] = fmaxf(v[1], 0.f);
        v[2] = fmaxf(v[2], 0.f); v[3] = fmaxf(v[3], 0.f);
        p[i] = v;
    }
}

extern "C" void kernel_launch(void* const* d_in, const int* in_sizes, int n_in,
                              void* d_out, int out_size, void* d_ws, size_t ws_size,
                              hipStream_t stream) {
    const float* x    = (const float*)d_in[0];
    const float* adj  = (const float*)d_in[1];
    const float* W    = (const float*)d_in[2];
    const float* bias = (const float*)d_in[3];
    float* out = (float*)d_out;
    short* sup = (short*)d_ws;            // 32 MB of ws
    short* Wt  = (short*)d_out;           // 1 MB scratch inside d_out, consumed before memset

    prep_w_kernel<<<dim3(4, 4, 8), 256, 0, stream>>>(W, Wt);
    support_kernel<<<dim3(2, 8, 64), 256, 0, stream>>>(x, Wt, bias, sup);
    hipMemsetAsync(d_out, 0, (size_t)out_size * sizeof(float), stream);
    gcn_gemm_kernel<<<dim3(16, 8, 8), 256, 0, stream>>>(adj, sup, out);
    relu_kernel<<<(out_size / 4 + 255) / 256, 256, 0, stream>>>(out, out_size / 4);
}